// Round 7
// baseline (1027.879 us; speedup 1.0000x reference)
//
#include <hip/hip_runtime.h>

#define NN     50000
#define NRELB  20
#define RR     (2*NRELB + 1)      // 41
#define NHID   16
#define NCLASS 50
#define EB     1600000
#define WPB    4                  // waves per block (layer1)
#define NPB    8                  // nodes per block (agg) = waves per block
#define RH     (RR * NHID)        // 656
#define NPBRH  (NPB * RH)         // 5248
#define STRIDE 128                // static CSR bucket size (max deg ~65+8*sigma << 128)
#define KPAD   672                // 656 padded to 8*84
#define KU32   (KPAD/2)           // 336 u32 (bf16 pairs) per af row
#define KB     (KPAD/8)           // 84 k-blocks of 8
#define NROWS  50048              // 782*64 af rows (padded)

__device__ __forceinline__ unsigned bf16r(float x) {     // fp32 -> bf16 bits, RNE
    unsigned b = __float_as_uint(x);
    return (b + 0x7fffu + ((b >> 16) & 1u)) >> 16;
}

// Seed each node's bucket with its self-loop at slot 0.
__global__ void init_kernel(unsigned* __restrict__ cnt, unsigned* __restrict__ ekey) {
    int n = blockIdx.x * blockDim.x + threadIdx.x;
    if (n >= NN) return;
    cnt[n] = 1u;
    ekey[(size_t)n * STRIDE] = ((unsigned)(2 * NRELB) << 16) | (unsigned)n;
}

// One thread per base edge: emit forward + inverse into static buckets.
__global__ void scatter_kernel(const int* __restrict__ src, const int* __restrict__ rel,
                               const int* __restrict__ dst,
                               unsigned* __restrict__ cnt, unsigned* __restrict__ ekey) {
    int e = blockIdx.x * blockDim.x + threadIdx.x;
    if (e >= EB) return;
    int s = src[e], r = rel[e], o = dst[e];
    unsigned p1 = atomicAdd(&cnt[s], 1u);
    ekey[(size_t)s * STRIDE + p1] = ((unsigned)r << 16) | (unsigned)o;
    unsigned p2 = atomicAdd(&cnt[o], 1u);
    ekey[(size_t)o * STRIDE + p2] = ((unsigned)(r + NRELB) << 16) | (unsigned)s;
}

// Layer 1: one wave per node, h-major LDS [h*41+r], 2-deep pipelined edge loop.
__global__ __launch_bounds__(256) void layer1_kernel(
        const unsigned* __restrict__ ekey, const unsigned* __restrict__ cnt,
        const float* __restrict__ W1, const float* __restrict__ b1,
        float* __restrict__ h) {
    __shared__ float acc[WPB][RH];      // [h*41 + r]
    __shared__ float degL[WPB][RR];
    const int wave = threadIdx.x >> 6, lane = threadIdx.x & 63;
    const int n = blockIdx.x * WPB + wave;
    for (int i = lane; i < RH; i += 64) acc[wave][i] = 0.f;
    if (lane < RR) degL[wave][lane] = 0.f;
    __syncthreads();
    if (n < NN) {
        const int deg = cnt[n];
        const int g = lane >> 2, q = (lane & 3) * 4;
        const unsigned* ek = ekey + (size_t)n * STRIDE;
        for (int i = g; i < deg; i += 32) {
            unsigned k0 = ek[i];
            int r0 = k0 >> 16, o0 = k0 & 0xFFFF;
            float4 v0 = *(const float4*)(W1 + ((size_t)(r0 * NN + o0)) * NHID + q);
            const bool has1 = (i + 16) < deg;
            unsigned k1 = 0; float4 v1 = v0; int r1 = 0;
            if (has1) {
                k1 = ek[i + 16];
                r1 = k1 >> 16;
                v1 = *(const float4*)(W1 + ((size_t)(r1 * NN + (k1 & 0xFFFF))) * NHID + q);
            }
            atomicAdd(&acc[wave][(q + 0) * RR + r0], v0.x);
            atomicAdd(&acc[wave][(q + 1) * RR + r0], v0.y);
            atomicAdd(&acc[wave][(q + 2) * RR + r0], v0.z);
            atomicAdd(&acc[wave][(q + 3) * RR + r0], v0.w);
            if ((lane & 3) == 0) atomicAdd(&degL[wave][r0], 1.f);
            if (has1) {
                atomicAdd(&acc[wave][(q + 0) * RR + r1], v1.x);
                atomicAdd(&acc[wave][(q + 1) * RR + r1], v1.y);
                atomicAdd(&acc[wave][(q + 2) * RR + r1], v1.z);
                atomicAdd(&acc[wave][(q + 3) * RR + r1], v1.w);
                if ((lane & 3) == 0) atomicAdd(&degL[wave][r1], 1.f);
            }
        }
    }
    __syncthreads();
    if (lane < RR) {            // deg -> 1/deg in place
        float d = degL[wave][lane];
        degL[wave][lane] = (d != 0.f) ? 1.f / d : 0.f;
    }
    __syncthreads();
    if (n < NN) {
        const int g = lane >> 4, hh = lane & 15;
        float sum = 0.f;
        for (int r = g; r < RR; r += 4)
            sum += acc[wave][hh * RR + r] * degL[wave][r];
        sum += __shfl_xor(sum, 16);
        sum += __shfl_xor(sum, 32);
        if (lane < NHID) h[n * NHID + lane] = fmaxf(sum + b1[lane], 0.f);
    }
}

// Layer-2 aggregation: 512 threads, 1 node/wave. Accumulate h[o] per (r,h) in LDS,
// scale by 1/deg, emit af row as packed bf16 pairs (k = r*16+h, padded to 672).
__global__ __launch_bounds__(512) void agg_kernel(
        const unsigned* __restrict__ ekey, const unsigned* __restrict__ cnt,
        const float* __restrict__ h, unsigned* __restrict__ af) {
    __shared__ float buf[NPBRH];               // [nd][hh*41 + r]
    __shared__ float degL[NPB * RR];
    const int tid = threadIdx.x, wave = tid >> 6, lane = tid & 63;
    const int nbase = blockIdx.x * NPB;

    for (int i = tid; i < NPBRH; i += 512) buf[i] = 0.f;
    if (tid < NPB * RR) degL[tid] = 0.f;
    __syncthreads();

    {   // Phase A: accumulate; 2-deep pipelined, 4 lanes/edge
        const int nd = wave;
        const int n = nbase + nd;
        const int deg = cnt[n];
        const int g = lane >> 2, q = (lane & 3) * 4;
        const unsigned* ek = ekey + (size_t)n * STRIDE;
        float* base = &buf[nd * RH];
        for (int i = g; i < deg; i += 32) {
            unsigned k0 = ek[i];
            int r0 = k0 >> 16;
            float4 v0 = *(const float4*)(h + (k0 & 0xFFFF) * NHID + q);
            const bool has1 = (i + 16) < deg;
            unsigned k1 = 0; float4 v1 = v0; int r1 = 0;
            if (has1) {
                k1 = ek[i + 16];
                r1 = k1 >> 16;
                v1 = *(const float4*)(h + (k1 & 0xFFFF) * NHID + q);
            }
            atomicAdd(base + (q + 0) * RR + r0, v0.x);
            atomicAdd(base + (q + 1) * RR + r0, v0.y);
            atomicAdd(base + (q + 2) * RR + r0, v0.z);
            atomicAdd(base + (q + 3) * RR + r0, v0.w);
            if ((lane & 3) == 0) atomicAdd(&degL[nd * RR + r0], 1.f);
            if (has1) {
                atomicAdd(base + (q + 0) * RR + r1, v1.x);
                atomicAdd(base + (q + 1) * RR + r1, v1.y);
                atomicAdd(base + (q + 2) * RR + r1, v1.z);
                atomicAdd(base + (q + 3) * RR + r1, v1.w);
                if ((lane & 3) == 0) atomicAdd(&degL[nd * RR + r1], 1.f);
            }
        }
    }
    __syncthreads();
    if (tid < NPB * RR) {                      // deg -> 1/deg
        float d = degL[tid];
        degL[tid] = (d != 0.f) ? 1.f / d : 0.f;
    }
    __syncthreads();

    {   // write af row: u32 idx -> bf16 pair (k=2*idx, 2*idx+1)
        const int nd = wave;
        unsigned* arow = af + (size_t)(nbase + nd) * KU32;
        for (int idx = lane; idx < KU32; idx += 64) {
            int rh0 = 2 * idx, rh1 = rh0 + 1;
            float v0 = 0.f, v1 = 0.f;
            if (rh0 < RH) v0 = buf[nd * RH + (rh0 & 15) * RR + (rh0 >> 4)]
                             * degL[nd * RR + (rh0 >> 4)];
            if (rh1 < RH) v1 = buf[nd * RH + (rh1 & 15) * RR + (rh1 >> 4)]
                             * degL[nd * RR + (rh1 >> 4)];
            arow[idx] = bf16r(v0) | (bf16r(v1) << 16);
        }
    }
}

// Pre-pack W2 (fp32) per-lane contiguous: W2pk[(kb*64+lane)*8 + j] = W2[kb*8+j][lane]
__global__ void pack_kernel(const float* __restrict__ W2, float* __restrict__ W2pk) {
    int idx = blockIdx.x * blockDim.x + threadIdx.x;
    if (idx >= KB * 64 * 8) return;
    int j = idx & 7, lane = (idx >> 3) & 63, kb = idx >> 9;
    int k = kb * 8 + j;
    W2pk[idx] = (k < RH && lane < NCLASS) ? W2[k * NCLASS + lane] : 0.f;
}

// GEMM + log-softmax: wave = 8 nodes, lane = class. af rows via wave-uniform
// scalar loads; W2pk via per-lane contiguous float4 pairs. No LDS.
__global__ __launch_bounds__(512) void gemm_kernel(
        const unsigned* __restrict__ af, const float* __restrict__ W2pk,
        const float* __restrict__ b2, float* __restrict__ out) {
    const int tid = threadIdx.x;
    const int wv = __builtin_amdgcn_readfirstlane(tid >> 6);
    const int lane = tid & 63;
    const int nbase = blockIdx.x * 64 + wv * 8;

    const uint4* a0 = (const uint4*)(af + (size_t)(nbase + 0) * KU32);
    const uint4* a1 = (const uint4*)(af + (size_t)(nbase + 1) * KU32);
    const uint4* a2 = (const uint4*)(af + (size_t)(nbase + 2) * KU32);
    const uint4* a3 = (const uint4*)(af + (size_t)(nbase + 3) * KU32);
    const uint4* a4 = (const uint4*)(af + (size_t)(nbase + 4) * KU32);
    const uint4* a5 = (const uint4*)(af + (size_t)(nbase + 5) * KU32);
    const uint4* a6 = (const uint4*)(af + (size_t)(nbase + 6) * KU32);
    const uint4* a7 = (const uint4*)(af + (size_t)(nbase + 7) * KU32);

    float acc[8];
    #pragma unroll
    for (int q = 0; q < 8; ++q) acc[q] = 0.f;

    const float* wbase = W2pk + (size_t)lane * 8;
    for (int kb = 0; kb < KB; ++kb) {
        float4 wA = *(const float4*)(wbase + (size_t)kb * 512);
        float4 wB = *(const float4*)(wbase + (size_t)kb * 512 + 4);
        uint4 a[8];
        a[0] = a0[kb]; a[1] = a1[kb]; a[2] = a2[kb]; a[3] = a3[kb];
        a[4] = a4[kb]; a[5] = a5[kb]; a[6] = a6[kb]; a[7] = a7[kb];
        #pragma unroll
        for (int q = 0; q < 8; ++q) {
            uint4 v = a[q];
            acc[q] += __uint_as_float(v.x << 16)         * wA.x
                    + __uint_as_float(v.x & 0xffff0000u) * wA.y
                    + __uint_as_float(v.y << 16)         * wA.z
                    + __uint_as_float(v.y & 0xffff0000u) * wA.w
                    + __uint_as_float(v.z << 16)         * wB.x
                    + __uint_as_float(v.z & 0xffff0000u) * wB.y
                    + __uint_as_float(v.w << 16)         * wB.z
                    + __uint_as_float(v.w & 0xffff0000u) * wB.w;
        }
    }

    const float bias = (lane < NCLASS) ? b2[lane] : 0.f;
    #pragma unroll
    for (int q = 0; q < 8; ++q) {
        const int n = nbase + q;
        if (n < NN) {
            float x = (lane < NCLASS) ? acc[q] + bias : -INFINITY;
            float m = x;
            #pragma unroll
            for (int off = 32; off; off >>= 1) m = fmaxf(m, __shfl_xor(m, off));
            float ex = (lane < NCLASS) ? expf(x - m) : 0.f;
            float ss = ex;
            #pragma unroll
            for (int off = 32; off; off >>= 1) ss += __shfl_xor(ss, off);
            float ls = logf(ss) + m;
            if (lane < NCLASS) out[n * NCLASS + lane] = x - ls;
        }
    }
}

extern "C" void kernel_launch(void* const* d_in, const int* in_sizes, int n_in,
                              void* d_out, int out_size, void* d_ws, size_t ws_size,
                              hipStream_t stream) {
    const int*   src = (const int*)d_in[0];
    const int*   rel = (const int*)d_in[1];
    const int*   dst = (const int*)d_in[2];
    const float* W1  = (const float*)d_in[3];
    const float* b1  = (const float*)d_in[4];
    const float* W2  = (const float*)d_in[5];
    const float* b2  = (const float*)d_in[6];
    float* out = (float*)d_out;

    unsigned* cnt  = (unsigned*)d_ws;                        // NN
    unsigned* ekey = cnt + NN;                               // NN*STRIDE (25.6 MB)
    float*    h    = (float*)(ekey + (size_t)NN * STRIDE);   // NN*NHID (3.2 MB)
    unsigned* af   = (unsigned*)(h + (size_t)NN * NHID);     // NROWS*KU32 (67.3 MB)
    float*    W2pk = (float*)(af + (size_t)NROWS * KU32);    // KB*512 (172 KB)

    const int blk = 256;
    init_kernel<<<(NN + blk - 1) / blk, blk, 0, stream>>>(cnt, ekey);
    scatter_kernel<<<(EB + blk - 1) / blk, blk, 0, stream>>>(src, rel, dst, cnt, ekey);
    pack_kernel<<<(KB * 512 + blk - 1) / blk, blk, 0, stream>>>(W2, W2pk);
    layer1_kernel<<<NN / WPB, blk, 0, stream>>>(ekey, cnt, W1, b1, h);
    agg_kernel<<<NN / NPB, 512, 0, stream>>>(ekey, cnt, h, af);
    gemm_kernel<<<(NN + 63) / 64, 512, 0, stream>>>(af, W2pk, b2, out);
}